// Round 1
// baseline (831.403 us; speedup 1.0000x reference)
//
#include <hip/hip_runtime.h>
#include <math.h>

static constexpr int N = 100000;

// ---------------- degree (with self-loop) ----------------
__global__ void k_deg_init(float* __restrict__ deg) {
    int i = blockIdx.x * blockDim.x + threadIdx.x;
    if (i < N) deg[i] = 1.0f;   // self-loop contributes 1
}

__global__ void k_deg_count(const int* __restrict__ dst, float* __restrict__ deg, int E) {
    int e = blockIdx.x * blockDim.x + threadIdx.x;
    if (e < E) atomicAdd(deg + dst[e], 1.0f);
}

// ---------------- layer 1 transform: g1 = dis * (x @ W1^T), acc1 = g1 ----------------
// x: [N,128], W1: [32,128]. 8 nodes per 256-thread block; thread = (node_local<<5)|j.
__global__ __launch_bounds__(256) void k_xw1(
        const float* __restrict__ x, const float* __restrict__ W1,
        const float* __restrict__ deg,
        float* __restrict__ g1, float* __restrict__ acc1) {
    __shared__ float wt[128 * 33];   // W1 transposed [k][j], pad 33 -> conflict-free
    __shared__ float xs[8 * 128];
    const int t = threadIdx.x;
    for (int idx = t; idx < 4096; idx += 256) {
        int j = idx >> 7, k = idx & 127;
        wt[k * 33 + j] = W1[idx];
    }
    // 8 consecutive nodes x 128 floats are contiguous: one float4 per thread
    const float4* x4 = (const float4*)x + (size_t)blockIdx.x * 256;
    ((float4*)xs)[t] = x4[t];
    __syncthreads();

    const int nl = t >> 5, j = t & 31;
    const int node = blockIdx.x * 8 + nl;
    const float* xr = xs + nl * 128;
    float a = 0.f;
#pragma unroll 8
    for (int k = 0; k < 128; ++k) a = fmaf(xr[k], wt[k * 33 + j], a);
    const float v = a * rsqrtf(deg[node]);
    const int o = blockIdx.x * 256 + t;   // node*32 + j
    g1[o] = v;
    acc1[o] = v;   // self-loop term pre-seeded
}

// ---------------- edge scatter, 32 features: acc1[dst] += g1[src] ----------------
__global__ __launch_bounds__(256) void k_scatter1(
        const int* __restrict__ src, const int* __restrict__ dst,
        const float* __restrict__ g1, float* __restrict__ acc1, int E) {
    const int t = threadIdx.x;
    const int e = blockIdx.x * 8 + (t >> 5);
    if (e >= E) return;
    const int j = t & 31;
    const int s = src[e], d = dst[e];
    atomicAdd(acc1 + d * 32 + j, g1[s * 32 + j]);
}

// ---------------- layer 2: h1=relu(dis*acc1+b1); g2 = dis*(h1@W2^T); acc2 = g2 ----------------
// W2: [16,32]. 16 nodes per block; thread = (node_local<<4)|j.
__global__ __launch_bounds__(256) void k_layer2(
        const float* __restrict__ acc1, const float* __restrict__ W2,
        const float* __restrict__ b1, const float* __restrict__ deg,
        float* __restrict__ g2, float* __restrict__ acc2) {
    __shared__ float h1s[16 * 32];
    __shared__ float w2t[32 * 17];   // [k][j], pad 17
    const int t = threadIdx.x;
    for (int idx = t; idx < 512; idx += 256) {
        int j = idx >> 5, k = idx & 31;
        w2t[k * 17 + j] = W2[idx];
    }
    const int base = blockIdx.x * 512;
    for (int idx = t; idx < 512; idx += 256) {
        int nl = idx >> 5, k = idx & 31;
        int node = blockIdx.x * 16 + nl;
        float v = acc1[base + idx] * rsqrtf(deg[node]) + b1[k];
        h1s[idx] = v > 0.f ? v : 0.f;
    }
    __syncthreads();
    const int nl = t >> 4, j = t & 15;
    const int node = blockIdx.x * 16 + nl;
    const float* hr = h1s + nl * 32;
    float a = 0.f;
#pragma unroll
    for (int k = 0; k < 32; ++k) a = fmaf(hr[k], w2t[k * 17 + j], a);
    const float v = a * rsqrtf(deg[node]);
    const int o = blockIdx.x * 256 + t;   // node*16 + j
    g2[o] = v;
    acc2[o] = v;
}

// ---------------- edge scatter, 16 features ----------------
__global__ __launch_bounds__(256) void k_scatter2(
        const int* __restrict__ src, const int* __restrict__ dst,
        const float* __restrict__ g2, float* __restrict__ acc2, int E) {
    const int t = threadIdx.x;
    const int e = blockIdx.x * 16 + (t >> 4);
    if (e >= E) return;
    const int j = t & 15;
    const int s = src[e], d = dst[e];
    atomicAdd(acc2 + d * 16 + j, g2[s * 16 + j]);
}

// ---------------- finalize layer2 + LSTM (h0=c0=0) + output head ----------------
__global__ __launch_bounds__(256) void k_final(
        const float* __restrict__ acc2, const float* __restrict__ deg,
        const float* __restrict__ b2,
        const float* __restrict__ w_ih, const float* __restrict__ b_ih,
        const float* __restrict__ b_hh, const float* __restrict__ W_out,
        const float* __restrict__ b_out, float* __restrict__ out) {
    __shared__ float wih[512];
    __shared__ float bias[32];
    __shared__ float b2s[16];
    __shared__ float wout[8];
    __shared__ float bo;
    const int t = threadIdx.x;
    for (int idx = t; idx < 512; idx += 256) wih[idx] = w_ih[idx];
    if (t < 32) bias[t] = b_ih[t] + b_hh[t];
    if (t < 16) b2s[t] = b2[t];
    if (t < 8)  wout[t] = W_out[t];
    if (t == 0) bo = b_out[0];
    __syncthreads();

    const int i = blockIdx.x * 256 + t;
    if (i >= N) return;
    const float dis = rsqrtf(deg[i]);
    float h2[16];
    const float4* a4 = (const float4*)(acc2 + (size_t)i * 16);
#pragma unroll
    for (int q = 0; q < 4; ++q) {
        float4 v = a4[q];
        float vv[4] = {v.x, v.y, v.z, v.w};
#pragma unroll
        for (int r = 0; r < 4; ++r) {
            float h = vv[r] * dis + b2s[q * 4 + r];
            h2[q * 4 + r] = h > 0.f ? h : 0.f;
        }
    }
    float oacc = 0.f;
#pragma unroll
    for (int q = 0; q < 8; ++q) {
        float gi = bias[q], gg = bias[16 + q], go = bias[24 + q];
#pragma unroll
        for (int k = 0; k < 16; ++k) {
            gi = fmaf(h2[k], wih[q * 16 + k], gi);
            gg = fmaf(h2[k], wih[(16 + q) * 16 + k], gg);
            go = fmaf(h2[k], wih[(24 + q) * 16 + k], go);
        }
        float c  = (1.f / (1.f + expf(-gi))) * tanhf(gg);
        float hh = (1.f / (1.f + expf(-go))) * tanhf(c);
        oacc = fmaf(hh, wout[q], oacc);
    }
    out[i] = oacc + bo;
}

extern "C" void kernel_launch(void* const* d_in, const int* in_sizes, int n_in,
                              void* d_out, int out_size, void* d_ws, size_t ws_size,
                              hipStream_t stream) {
    const float* x     = (const float*)d_in[0];
    const int*   ei    = (const int*)d_in[1];
    const float* W1    = (const float*)d_in[2];
    const float* b1    = (const float*)d_in[3];
    const float* W2    = (const float*)d_in[4];
    const float* b2    = (const float*)d_in[5];
    const float* w_ih  = (const float*)d_in[6];
    // d_in[7] = w_hh: unused (h0 = 0)
    const float* b_ih  = (const float*)d_in[8];
    const float* b_hh  = (const float*)d_in[9];
    const float* W_out = (const float*)d_in[10];
    const float* b_out = (const float*)d_in[11];
    float* out = (float*)d_out;

    const int E = in_sizes[1] / 2;
    const int* src = ei;
    const int* dst = ei + E;

    float* ws  = (float*)d_ws;
    float* deg  = ws;                       // N floats
    float* g1   = ws + N;                   // N*32
    float* acc1 = g1 + (size_t)N * 32;      // N*32
    float* g2   = g1;                       // reuse g1 region (dead after scatter1): N*16
    float* acc2 = g1 + (size_t)N * 16;      // N*16

    k_deg_init <<<(N + 255) / 256, 256, 0, stream>>>(deg);
    k_deg_count<<<(E + 255) / 256, 256, 0, stream>>>(dst, deg, E);
    k_xw1      <<<N / 8,            256, 0, stream>>>(x, W1, deg, g1, acc1);
    k_scatter1 <<<(E + 7) / 8,      256, 0, stream>>>(src, dst, g1, acc1, E);
    k_layer2   <<<N / 16,           256, 0, stream>>>(acc1, W2, b1, deg, g2, acc2);
    k_scatter2 <<<(E + 15) / 16,    256, 0, stream>>>(src, dst, g2, acc2, E);
    k_final    <<<(N + 255) / 256,  256, 0, stream>>>(acc2, deg, b2, w_ih, b_ih, b_hh, W_out, b_out, out);
}